// Round 7
// baseline (219.652 us; speedup 1.0000x reference)
//
#include <hip/hip_runtime.h>

// Problem constants
#define B_DIM 32
#define V_DIM 21
#define D_DIM 512
#define P_DIM 64
#define M_TOTAL 672          // B*V
#define K_TOTAL 32768        // D*P
#define OUT_DIM 96
#define E_DIM 8
#define R_DIM 8
#define H_DIM 256
#define N_TOTAL 160          // OUT_DIM + E*R
#define SCALING 2.0f
#define POOL_SCALE (1.0f / (V_DIM * (float)P_DIM))

// GEMM: barrier-free all-register pipeline. BM=96 (7 blocks exact), 6 waves.
#define BM 96
#define BK 32
#define KSPLIT 32
#define K_PER_SPLIT (K_TOTAL / KSPLIT)   // 1024
#define CHUNKS (K_PER_SPLIT / BK)        // 32
#define SMN (M_TOTAL * N_TOTAL)          // 107520 per partial plane
#define NMB 7                            // m-blocks (7*96 = 672 exact)
#define RC_ROWS 4                        // rows per reduce_combine block

typedef __attribute__((ext_vector_type(4))) float floatx4;
typedef __attribute__((ext_vector_type(8))) short short8;

__device__ __forceinline__ unsigned short f2bf(float f) {
  union { float f; unsigned int u; } v; v.f = f;
  unsigned int u = v.u + (0x7FFFu + ((v.u >> 16) & 1u));  // RNE
  return (unsigned short)(u >> 16);
}

// v_cvt_pk_bf16_f32: RNE, lo -> bits[15:0], hi -> bits[31:16] (matches f2bf)
__device__ __forceinline__ unsigned int cvt_pk_bf16(float lo, float hi) {
  unsigned int r;
  asm("v_cvt_pk_bf16_f32 %0, %1, %2" : "=v"(r) : "v"(lo), "v"(hi));
  return r;
}

// ------- convW: [W_base|lora_A] fp32 -> bf16 Wb in FRAGMENT-MAJOR layout:
// offset = ((ky*32 + c)*10 + nt)*512 + l16*32 + quad*8, where row = nt*16+l16,
// k = ky*1024 + c*32 + quad*8 + j. Each gemm B-fragment load (64 lanes over
// l16 x quad) is then 1KB CONTIGUOUS -> fully coalesced, L1-friendly.
__global__ __launch_bounds__(256)
void convW_kernel(const float* __restrict__ W_base, const float* __restrict__ lora_A,
                  short* __restrict__ Wb) {
  int gid = blockIdx.x * 256 + threadIdx.x;
  size_t base = (size_t)gid * 8;          // element index (8-aligned)
  int row = (int)(base >> 15);
  int k = (int)(base & 32767);
  const float* src = (row < OUT_DIM) ? (W_base + ((size_t)row << 15) + k)
                                     : (lora_A + ((size_t)(row - OUT_DIM) << 15) + k);
  floatx4 v0 = ((const floatx4*)src)[0];
  floatx4 v1 = ((const floatx4*)src)[1];
  short8 sv;
  sv[0] = (short)f2bf(v0[0]); sv[1] = (short)f2bf(v0[1]);
  sv[2] = (short)f2bf(v0[2]); sv[3] = (short)f2bf(v0[3]);
  sv[4] = (short)f2bf(v1[0]); sv[5] = (short)f2bf(v1[1]);
  sv[6] = (short)f2bf(v1[2]); sv[7] = (short)f2bf(v1[3]);
  int ky = k >> 10, c = (k >> 5) & 31, quad = (k >> 3) & 3;
  int nt = row >> 4, l16 = row & 15;
  size_t off = ((size_t)(ky * 32 + c) * 10 + nt) * 512 + l16 * 32 + quad * 8;
  *(short8*)(Wb + off) = sv;
}

// ------- gemm v7: barrier-free, all-register. Every lane streams its own A
// (depth-4) and B fragments (depth-2, fragment-major Wb) straight from cache;
// no LDS tiles, no mid-loop barriers, no hand vmcnt -- compiler inserts
// precise waits; waves slip freely (no convoy). 6 waves x 16 rows = 96 rows.
// Pooling in registers, flushed to lds_pool per d (atomics, init published by
// one prologue barrier). Grid 224 = 7mb x 32ky <= 256 CUs: single round;
// XCD-grouped so 7 same-ky blocks share the Wb k-slice in their XCD's L2.
__global__ __launch_bounds__(384)
void gemm_kernel(const float* __restrict__ x, const short* __restrict__ Wb,
                 float* __restrict__ P, float* __restrict__ pp) {
  __shared__ float lds_pool[6 * 16];      // [b_local][d_local]

  const int tid = threadIdx.x;
  const int bid = blockIdx.x;
  const int xcd = bid & 7;
  const int grp = bid >> 3;               // 0..27
  const int ky  = xcd + 8 * (grp / NMB);  // 0..31
  const int mb  = grp % NMB;              // 0..6
  const int m0 = mb * BM;
  const int kbase = ky * K_PER_SPLIT;
  const int lane = tid & 63;
  const int wave = tid >> 6;              // 0..5
  const int quad = lane >> 4;
  const int l16 = lane & 15;
  const int b_first = m0 / V_DIM;

  if (tid < 96) lds_pool[tid] = 0.0f;
  asm volatile("s_waitcnt lgkmcnt(0)" ::: "memory");
  __builtin_amdgcn_s_barrier();           // publish pool zeros (only barrier)

  // A: lane (l16,quad) owns row m0+wave*16+l16, k-window quad*8 within chunk.
  const int arow = m0 + wave * 16 + l16;  // always < 672 (7*96 exact)
  const floatx4* aptr =
      (const floatx4*)(x + (size_t)arow * K_TOTAL + kbase + quad * 8);
  // B: fragment-major; chunk c, tile nt at bbase + c*5120 + nt*512 (shorts).
  const short* bbase = Wb + (size_t)ky * (CHUNKS * 5120) + l16 * 32 + quad * 8;
  const int pool_idx = (arow / V_DIM - b_first) * 16;

  short8 bf[2][10];                       // B depth-2 (2 chunk-bodies slack)
  floatx4 af[4][2];                       // A depth-4 (covers HBM latency)
  floatx4 acc[10];
  #pragma unroll
  for (int nt = 0; nt < 10; ++nt) acc[nt] = (floatx4)(0.0f);
  floatx4 paccv = (floatx4)(0.0f);

  #pragma unroll
  for (int nt = 0; nt < 10; ++nt)
    bf[0][nt] = *(const short8*)(bbase + nt * 512);
  #pragma unroll
  for (int nt = 0; nt < 10; ++nt)
    bf[1][nt] = *(const short8*)(bbase + 5120 + nt * 512);
  af[0][0] = aptr[0];  af[0][1] = aptr[1];
  af[1][0] = aptr[8];  af[1][1] = aptr[9];
  af[2][0] = aptr[16]; af[2][1] = aptr[17];
  af[3][0] = aptr[24]; af[3][1] = aptr[25];

  #pragma unroll
  for (int c = 0; c < CHUNKS; ++c) {
    const int ab = c & 3, bb = c & 1;     // static after full unroll
    floatx4 f0 = af[ab][0], f1 = af[ab][1];
    if (c + 4 < CHUNKS) {                 // refill A slot with chunk c+4
      af[ab][0] = aptr[(c + 4) * 8];
      af[ab][1] = aptr[(c + 4) * 8 + 1];
    }
    union { short8 s; unsigned int u[4]; } av;
    av.u[0] = cvt_pk_bf16(f0[0], f0[1]);
    av.u[1] = cvt_pk_bf16(f0[2], f0[3]);
    av.u[2] = cvt_pk_bf16(f1[0], f1[1]);
    av.u[3] = cvt_pk_bf16(f1[2], f1[3]);
    paccv += f0 + f1;
    if (c & 1) {                          // d-boundary: flush row-sum, d = c>>1
      float h = (paccv[0] + paccv[1]) + (paccv[2] + paccv[3]);
      h += __shfl_down(h, 32);
      h += __shfl_down(h, 16);
      if (lane < 16)
        atomicAdd(&lds_pool[pool_idx + (c >> 1)], h);
      paccv = (floatx4)(0.0f);
    }
    #pragma unroll
    for (int nt = 0; nt < 10; ++nt)
      acc[nt] = __builtin_amdgcn_mfma_f32_16x16x32_bf16(av.s, bf[bb][nt],
                                                        acc[nt], 0, 0, 0);
    if (c + 2 < CHUNKS) {                 // refill B buffer with chunk c+2
      #pragma unroll
      for (int nt = 0; nt < 10; ++nt)
        bf[bb][nt] = *(const short8*)(bbase + (c + 2) * 5120 + nt * 512);
    }
  }

  __syncthreads();                        // pool atomics visible

  // partial-plane store (D layout: col=lane&15, row=quad*4+reg)
  {
    const int mrow = m0 + wave * 16 + quad * 4;
    float* Pp = P + (size_t)ky * SMN + (size_t)mrow * N_TOTAL + l16;
    #pragma unroll
    for (int r = 0; r < 4; ++r)
      #pragma unroll
      for (int nt = 0; nt < 10; ++nt)
        Pp[(size_t)r * N_TOTAL + nt * 16] = acc[nt][r];
  }

  // pooled partials: unique owner (mb, bl, d) -> plain store, no atomics
  if (tid < 96) {
    int bl = tid >> 4, dl = tid & 15;
    pp[((size_t)(mb * 6 + bl)) * D_DIM + ky * 16 + dl] = lds_pool[tid];
  }
}

// ---------------- router: gather pooled from pp, MLP + softmax + top-2 ------
__global__ __launch_bounds__(256)
void router_kernel(const float* __restrict__ pp, const float* __restrict__ W1,
                   const float* __restrict__ b1, const float* __restrict__ W2,
                   const float* __restrict__ b2, float* __restrict__ wfull,
                   float* __restrict__ probs_out) {
  __shared__ float sp[D_DIM];
  __shared__ float sh[H_DIM];
  __shared__ float slog[E_DIM];
  const int b = blockIdx.x;
  const int t = threadIdx.x;
  // rows of batch b live in m-blocks mb1..mb2 (at most 2)
  const int mb1 = (b * V_DIM) / BM;
  const int mb2 = (b * V_DIM + V_DIM - 1) / BM;
  const int bf1 = (mb1 * BM) / V_DIM;
  const int bf2 = (mb2 * BM) / V_DIM;
  const float* p1 = pp + (size_t)(mb1 * 6 + (b - bf1)) * D_DIM;
  const float* p2 = pp + (size_t)(mb2 * 6 + (b - bf2)) * D_DIM;
  for (int d = t; d < D_DIM; d += 256) {
    float v = p1[d];
    if (mb2 != mb1) v += p2[d];
    sp[d] = v * POOL_SCALE;
  }
  __syncthreads();
  float acc = b1[t];
  const float* w1r = W1 + (size_t)t * D_DIM;
  for (int d = 0; d < D_DIM; ++d) acc += sp[d] * w1r[d];
  sh[t] = fmaxf(acc, 0.0f);
  __syncthreads();
  if (t < E_DIM) {
    float a = b2[t];
    const float* w2r = W2 + t * H_DIM;
    for (int j = 0; j < H_DIM; ++j) a += sh[j] * w2r[j];
    slog[t] = a;
  }
  __syncthreads();
  if (t == 0) {
    float p[E_DIM];
    float mx = slog[0];
    for (int e = 1; e < E_DIM; ++e) mx = fmaxf(mx, slog[e]);
    float se = 0.0f;
    for (int e = 0; e < E_DIM; ++e) { p[e] = __expf(slog[e] - mx); se += p[e]; }
    float inv = 1.0f / se;
    for (int e = 0; e < E_DIM; ++e) { p[e] *= inv; probs_out[b * E_DIM + e] = p[e]; }
    // top-2, lowest index wins ties (strict > keeps earlier index)
    int i0 = 0;
    for (int e = 1; e < E_DIM; ++e) if (p[e] > p[i0]) i0 = e;
    int i1 = (i0 == 0) ? 1 : 0;
    for (int e = 0; e < E_DIM; ++e) if (e != i0 && p[e] > p[i1]) i1 = e;
    float s2 = p[i0] + p[i1];
    float invs = 1.0f / fmaxf(s2, 1e-6f);
    for (int e = 0; e < E_DIM; ++e) {
      float w = 0.0f;
      if (e == i0) w += p[i0] * invs;
      if (e == i1) w += p[i1] * invs;
      wfull[b * E_DIM + e] = w;
    }
  }
}

// ------- reduce partials over KSPLIT + combine: out = S_b + b_base + 2*Σ w·(S_l·B)
__global__ __launch_bounds__(256)
void reduce_combine_kernel(const float* __restrict__ P, const float* __restrict__ b_base,
                           const float* __restrict__ lora_B, const float* __restrict__ wfull,
                           float* __restrict__ out) {
  __shared__ float sS[RC_ROWS * N_TOTAL];   // 640 floats
  const int t = threadIdx.x;
  const int NF4 = RC_ROWS * N_TOTAL / 4;    // 160 float4 per block
  if (t < NF4) {
    const floatx4* P4 = (const floatx4*)P;
    size_t base = (size_t)blockIdx.x * NF4 + t;
    floatx4 a = (floatx4)(0.0f);
    #pragma unroll 8
    for (int k = 0; k < KSPLIT; ++k) a += P4[(size_t)k * (SMN / 4) + base];
    *(floatx4*)&sS[t * 4] = a;
  }
  __syncthreads();
  for (int i = t; i < RC_ROWS * OUT_DIM; i += 256) {
    int mr = i / OUT_DIM;
    int o = i - mr * OUT_DIM;
    int mm = blockIdx.x * RC_ROWS + mr;
    int b = mm / V_DIM;
    const float* srow = sS + mr * N_TOTAL;
    float res = srow[o] + b_base[o];
    float moe = 0.0f;
    #pragma unroll
    for (int e = 0; e < E_DIM; ++e) {
      float we = wfull[b * E_DIM + e];
      if (we != 0.0f) {
        const float* lb = lora_B + ((size_t)e * OUT_DIM + o) * R_DIM;
        float dd = 0.0f;
        #pragma unroll
        for (int r = 0; r < R_DIM; ++r) dd += srow[OUT_DIM + e * R_DIM + r] * lb[r];
        moe += we * dd;
      }
    }
    out[(size_t)mm * OUT_DIM + o] = res + SCALING * moe;
  }
}

extern "C" void kernel_launch(void* const* d_in, const int* in_sizes, int n_in,
                              void* d_out, int out_size, void* d_ws, size_t ws_size,
                              hipStream_t stream) {
  const float* x      = (const float*)d_in[0];
  const float* W_base = (const float*)d_in[1];
  const float* b_base = (const float*)d_in[2];
  const float* W1     = (const float*)d_in[3];
  const float* b1     = (const float*)d_in[4];
  const float* W2     = (const float*)d_in[5];
  const float* b2     = (const float*)d_in[6];
  const float* lora_A = (const float*)d_in[7];
  const float* lora_B = (const float*)d_in[8];
  float* out = (float*)d_out;

  // ws layout: pp[7*6*512 f] | wfull[256 f] | Wb[160*32768 bf16] | P[32*107520 f]
  float* ws    = (float*)d_ws;
  float* pp    = ws;
  float* wfull = ws + NMB * 6 * D_DIM;
  short* Wb    = (short*)(wfull + 256);
  float* P     = (float*)(Wb + (size_t)N_TOTAL * K_TOTAL);

  convW_kernel<<<(N_TOTAL * K_TOTAL / 8 + 255) / 256, 256, 0, stream>>>(
      W_base, lora_A, Wb);
  gemm_kernel<<<NMB * KSPLIT, 384, 0, stream>>>(x, Wb, P, pp);
  router_kernel<<<B_DIM, 256, 0, stream>>>(pp, W1, b1, W2, b2, wfull,
                                           out + (size_t)M_TOTAL * OUT_DIM);
  reduce_combine_kernel<<<M_TOTAL / RC_ROWS, 256, 0, stream>>>(
      P, b_base, lora_B, wfull, out);
}